// Round 9
// baseline (107.561 us; speedup 1.0000x reference)
//
#include <hip/hip_runtime.h>

// CurvatureLoss: B=4, N=4096, fp32.
// R9: R8 was LDS-pipe-bound: 2.1M ds_read_b128 x ~12cyc = 41us ~ 44us wall.
//  - 2 queries/lane (wave = 128 queries/candidate): ds_reads halve to 1.05M.
//  - dot chains packed across (q0,q1) as v2f -> v_pk_fma_f32 (18 FMA -> 9).
//  - pack kernel folded into knn (stage raw ori/adv, compute w in staging):
//    2 dispatches total (R8's 3rd launch cost ~9us of bench).
//  - 512-thr blocks x 8 waves, 1024 blocks = 8192 waves; 40 KB LDS
//    (16 KB tile then reused as merge scratch) -> 4 blk/CU = 32 waves/CU.
//  - partial = 16384 x 8cb x 40 B = 5.24 MB (< R8's proven 5.75 MB ws use).

constexpr int BB   = 4;
constexpr int NN   = 4096;
constexpr int QPG  = 128;            // queries per group/block
constexpr int NGRP = BB * NN / QPG;  // 128 groups
constexpr int WPB  = 8;              // waves per block
constexpr int CHK  = 64;             // candidates per wave-chunk
constexpr int CPB  = WPB * CHK;      // 512 candidates per block
constexpr int NCB  = NN / CPB;       // 8 chunk-blocks per group
constexpr int NBLK = NGRP * NCB;     // 1024 blocks
constexpr float NEGBIG = -3.402823466e+38f;

typedef float v2f __attribute__((ext_vector_type(2)));

__device__ __forceinline__ float fmed3(float a, float b, float c) {
    return __builtin_amdgcn_fmed3f(a, b, c);
}
__device__ __forceinline__ float embed6(float t, unsigned eb) {
    return __uint_as_float((__float_as_uint(t) & 0xFFFFFFC0u) | eb);
}

__global__ __launch_bounds__(512, 8) void knn_kernel(
    const float* __restrict__ ori, const float* __restrict__ adv,
    float* __restrict__ partial)
{
    const int tid  = threadIdx.x;
    const int lane = tid & 63;
    const int w    = tid >> 6;            // wave 0..7
    const int g    = blockIdx.x >> 3;     // group 0..127
    const int cb   = blockIdx.x & (NCB - 1);
    const int b    = g >> 5;              // batch
    const int gl   = g & 31;              // group within batch

    __shared__ __align__(16) float smem[WPB * QPG * 10];   // 40 KB
    float4* tile = (float4*)smem;                          // first 16 KB

    // stage 512 candidates: raw ori/adv -> {x,y,z, 0.5|c|^2} pairs
    {
        const int j = cb * CPB + tid;     // batch-local candidate
        const float* po = ori + ((size_t)b * NN + j) * 3;
        const float* pa = adv + ((size_t)b * NN + j) * 3;
        float x = po[0], y = po[1], z = po[2];
        tile[2 * tid]     = make_float4(x, y, z, 0.5f * (x * x + y * y + z * z));
        x = pa[0]; y = pa[1]; z = pa[2];
        tile[2 * tid + 1] = make_float4(x, y, z, 0.5f * (x * x + y * y + z * z));
    }

    // this lane's two queries: qb0 in [gl*128, +64), qb1 = qb0+64
    const int qb0 = gl * QPG + lane;
    const int qb1 = qb0 + 64;
    const float* q0o = ori + ((size_t)b * NN + qb0) * 3;
    const float* q1o = ori + ((size_t)b * NN + qb1) * 3;
    const float* q0a = adv + ((size_t)b * NN + qb0) * 3;
    const float* q1a = adv + ((size_t)b * NN + qb1) * 3;
    const v2f Qox = {q0o[0], q1o[0]}, Qoy = {q0o[1], q1o[1]}, Qoz = {q0o[2], q1o[2]};
    const v2f Qax = {q0a[0], q1a[0]}, Qay = {q0a[1], q1a[1]}, Qaz = {q0a[2], q1a[2]};

    __syncthreads();

    // top-3 trackers per query (max = closest); self key guaranteed rank-1
    float oA0 = NEGBIG, oB0 = NEGBIG, oC0 = NEGBIG;
    float oA1 = NEGBIG, oB1 = NEGBIG, oC1 = NEGBIG;
    float aA0 = NEGBIG, aB0 = NEGBIG, aC0 = NEGBIG;
    float aA1 = NEGBIG, aB1 = NEGBIG, aC1 = NEGBIG;
    float m0  = NEGBIG, m1  = NEGBIG;

    const float4* tw = tile + w * (CHK * 2);

    #pragma unroll 8
    for (int t = 0; t < CHK; ++t) {
        const float4 co = tw[2 * t];          // broadcast ds_read_b128
        const float4 ca = tw[2 * t + 1];
        const unsigned eb = (unsigned)(CHK - 1 - t);  // smaller t -> larger key

        // packed dot chains: key = q.c - 0.5|c|^2 for (q0,q1) simultaneously
        const v2f cw = { -co.w, -co.w };
        v2f ko = Qoz * (v2f){co.z, co.z} + cw;
        ko = Qoy * (v2f){co.y, co.y} + ko;
        ko = Qox * (v2f){co.x, co.x} + ko;
        v2f km = Qaz * (v2f){co.z, co.z} + cw;
        km = Qay * (v2f){co.y, co.y} + km;
        km = Qax * (v2f){co.x, co.x} + km;
        const v2f cv = { -ca.w, -ca.w };
        v2f ka = Qaz * (v2f){ca.z, ca.z} + cv;
        ka = Qay * (v2f){ca.y, ca.y} + ka;
        ka = Qax * (v2f){ca.x, ca.x} + ka;

        const float ko0 = embed6(ko.x, eb), ko1 = embed6(ko.y, eb);
        const float km0 = embed6(km.x, eb), km1 = embed6(km.y, eb);
        const float ka0 = embed6(ka.x, eb), ka1 = embed6(ka.y, eb);

        oC0 = fmed3(oB0, oC0, ko0); oB0 = fmed3(oA0, oB0, ko0); oA0 = fmaxf(oA0, ko0);
        oC1 = fmed3(oB1, oC1, ko1); oB1 = fmed3(oA1, oB1, ko1); oA1 = fmaxf(oA1, ko1);
        aC0 = fmed3(aB0, aC0, ka0); aB0 = fmed3(aA0, aB0, ka0); aA0 = fmaxf(aA0, ka0);
        aC1 = fmed3(aB1, aC1, ka1); aB1 = fmed3(aA1, aB1, ka1); aA1 = fmaxf(aA1, ka1);
        m0  = fmaxf(m0, km0);
        m1  = fmaxf(m1, km1);
    }

    // self-collapse (wave-uniform): chunk holds q0 iff chunk == gl*2, q1 iff +1
    const int chunk = cb * WPB + w;       // batch-local chunk 0..63
    if (chunk == gl * 2)     { oA0 = oB0; oB0 = oC0; aA0 = aB0; aB0 = aC0; }
    if (chunk == gl * 2 + 1) { oA1 = oB1; oB1 = oC1; aA1 = aB1; aB1 = aC1; }

    const int base = chunk * CHK;

    __syncthreads();                      // tile no longer needed; reuse smem
    {
        float* my0 = smem + (size_t)(w * QPG + lane) * 10;
        my0[0] = oA0; my0[1] = oB0; my0[2] = aA0; my0[3] = aB0; my0[4] = m0;
        my0[5] = __int_as_float(base + (CHK - 1 - (int)(__float_as_uint(oA0) & 63u)));
        my0[6] = __int_as_float(base + (CHK - 1 - (int)(__float_as_uint(oB0) & 63u)));
        my0[7] = __int_as_float(base + (CHK - 1 - (int)(__float_as_uint(aA0) & 63u)));
        my0[8] = __int_as_float(base + (CHK - 1 - (int)(__float_as_uint(aB0) & 63u)));
        my0[9] = __int_as_float(base + (CHK - 1 - (int)(__float_as_uint(m0)  & 63u)));
        float* my1 = smem + (size_t)(w * QPG + 64 + lane) * 10;
        my1[0] = oA1; my1[1] = oB1; my1[2] = aA1; my1[3] = aB1; my1[4] = m1;
        my1[5] = __int_as_float(base + (CHK - 1 - (int)(__float_as_uint(oA1) & 63u)));
        my1[6] = __int_as_float(base + (CHK - 1 - (int)(__float_as_uint(oB1) & 63u)));
        my1[7] = __int_as_float(base + (CHK - 1 - (int)(__float_as_uint(aA1) & 63u)));
        my1[8] = __int_as_float(base + (CHK - 1 - (int)(__float_as_uint(aB1) & 63u)));
        my1[9] = __int_as_float(base + (CHK - 1 - (int)(__float_as_uint(m1)  & 63u)));
    }
    __syncthreads();

    if (tid < QPG) {
        // merge 8 wave-chunks for query tid (ascending w = ascending j;
        // strict > keeps smaller global index on ties)
        const float* p = smem + (size_t)tid * 10;
        float ko0 = p[0], ko1 = p[1], ka0 = p[2], ka1 = p[3], km = p[4];
        int jo0 = __float_as_int(p[5]), jo1 = __float_as_int(p[6]);
        int ja0 = __float_as_int(p[7]), ja1 = __float_as_int(p[8]);
        int jm  = __float_as_int(p[9]);
        #pragma unroll
        for (int ww = 1; ww < WPB; ++ww) {
            const float* r = smem + (size_t)(ww * QPG + tid) * 10;
            float c0, c1; int j0, j1;
            c0 = r[0]; c1 = r[1]; j0 = __float_as_int(r[5]); j1 = __float_as_int(r[6]);
            if (c0 > ko0)      { ko1 = ko0; jo1 = jo0; ko0 = c0; jo0 = j0; }
            else if (c0 > ko1) { ko1 = c0; jo1 = j0; }
            if (c1 > ko1)      { ko1 = c1; jo1 = j1; }
            c0 = r[2]; c1 = r[3]; j0 = __float_as_int(r[7]); j1 = __float_as_int(r[8]);
            if (c0 > ka0)      { ka1 = ka0; ja1 = ja0; ka0 = c0; ja0 = j0; }
            else if (c0 > ka1) { ka1 = c0; ja1 = j0; }
            if (c1 > ka1)      { ka1 = c1; ja1 = j1; }
            if (r[4] > km)     { km = r[4]; jm = __float_as_int(r[9]); }
        }
        float* dst = partial + ((size_t)(g * QPG + tid) * NCB + cb) * 10;
        dst[0] = ko0; dst[1] = ko1; dst[2] = ka0; dst[3] = ka1; dst[4] = km;
        dst[5] = __int_as_float(jo0); dst[6] = __int_as_float(jo1);
        dst[7] = __int_as_float(ja0); dst[8] = __int_as_float(ja1);
        dst[9] = __int_as_float(jm);
    }
}

__device__ __forceinline__ float uad(const float* __restrict__ pts, int j,
                                     float px, float py, float pz,
                                     float nx, float ny, float nz) {
    const float* p = pts + (size_t)j * 3;
    const float vx = p[0] - px, vy = p[1] - py, vz = p[2] - pz;
    const float s  = vx * vx + vy * vy + vz * vz + 1e-12f;
    return fabsf((vx * nx + vy * ny + vz * nz) * (1.0f / sqrtf(s)));
}

__global__ __launch_bounds__(256) void merge_epilogue(
    const float* __restrict__ partial, const float* __restrict__ ori,
    const float* __restrict__ adv, const float* __restrict__ nrm,
    float* __restrict__ out)
{
    const int q  = blockIdx.x * 256 + threadIdx.x;   // 0..16383
    const int b  = q >> 12;
    const int qb = q & (NN - 1);

    const float* p = partial + (size_t)q * NCB * 10;
    float ko0 = p[0], ko1 = p[1], ka0 = p[2], ka1 = p[3], km = p[4];
    int jo0 = __float_as_int(p[5]), jo1 = __float_as_int(p[6]);
    int ja0 = __float_as_int(p[7]), ja1 = __float_as_int(p[8]);
    int jm  = __float_as_int(p[9]);
    #pragma unroll
    for (int cb = 1; cb < NCB; ++cb) {
        const float* r = p + cb * 10;
        float c0, c1; int j0, j1;
        c0 = r[0]; c1 = r[1]; j0 = __float_as_int(r[5]); j1 = __float_as_int(r[6]);
        if (c0 > ko0)      { ko1 = ko0; jo1 = jo0; ko0 = c0; jo0 = j0; }
        else if (c0 > ko1) { ko1 = c0; jo1 = j0; }
        if (c1 > ko1)      { ko1 = c1; jo1 = j1; }
        c0 = r[2]; c1 = r[3]; j0 = __float_as_int(r[7]); j1 = __float_as_int(r[8]);
        if (c0 > ka0)      { ka1 = ka0; ja1 = ja0; ka0 = c0; ja0 = j0; }
        else if (c0 > ka1) { ka1 = c0; ja1 = j0; }
        if (c1 > ka1)      { ka1 = c1; ja1 = j1; }
        if (r[4] > km)     { km = r[4]; jm = __float_as_int(r[9]); }
    }

    const float* ob = ori + (size_t)b * NN * 3;
    const float* ab = adv + (size_t)b * NN * 3;
    const float* nb = nrm + (size_t)b * NN * 3;

    const float qox = ob[3 * qb], qoy = ob[3 * qb + 1], qoz = ob[3 * qb + 2];
    const float qax = ab[3 * qb], qay = ab[3 * qb + 1], qaz = ab[3 * qb + 2];
    const float nx = nb[3 * qb], ny = nb[3 * qb + 1], nz = nb[3 * qb + 2];
    const float ok = 0.5f * (uad(ob, jo0, qox, qoy, qoz, nx, ny, nz) +
                             uad(ob, jo1, qox, qoy, qoz, nx, ny, nz));
    const float ax = nb[3 * jm], ay = nb[3 * jm + 1], az = nb[3 * jm + 2];
    const float ak = 0.5f * (uad(ab, ja0, qax, qay, qaz, ax, ay, az) +
                             uad(ab, ja1, qax, qay, qaz, ax, ay, az));
    const float d = ak - ok;
    float val = d * d;

    #pragma unroll
    for (int off = 32; off > 0; off >>= 1) val += __shfl_down(val, off);
    __shared__ float ls[4];
    if ((threadIdx.x & 63) == 0) ls[threadIdx.x >> 6] = val;
    __syncthreads();
    if (threadIdx.x == 0)
        atomicAdd(out, (ls[0] + ls[1] + ls[2] + ls[3]) * (1.0f / (float)(BB * NN)));
}

extern "C" void kernel_launch(void* const* d_in, const int* in_sizes, int n_in,
                              void* d_out, int out_size, void* d_ws, size_t ws_size,
                              hipStream_t stream) {
    const float* ori = (const float*)d_in[0];
    const float* adv = (const float*)d_in[1];
    const float* nrm = (const float*)d_in[2];
    float* out = (float*)d_out;

    float* part = (float*)d_ws;   // 16384 * 8 * 10 * 4 B = 5.24 MB
                                  // (ws proven >= 5.75 MB by R8's run)

    hipMemsetAsync(out, 0, sizeof(float), stream);
    hipLaunchKernelGGL(knn_kernel, dim3(NBLK), dim3(512), 0, stream,
                       ori, adv, part);
    hipLaunchKernelGGL(merge_epilogue, dim3(BB * NN / 256), dim3(256), 0, stream,
                       part, ori, adv, nrm, out);
}